// Round 2
// baseline (615.974 us; speedup 1.0000x reference)
//
#include <hip/hip_runtime.h>

typedef __bf16 bf16x8 __attribute__((ext_vector_type(8)));
typedef __bf16 bf16x4 __attribute__((ext_vector_type(4)));
typedef float  f32x4  __attribute__((ext_vector_type(4)));

static constexpr int Bb = 4, T = 8192, H = 1024, R = 1024;
static constexpr int BT = Bb * T;   // 32768 rows
static constexpr int N1 = 2 * R;    // 2048 (z|h columns)
static constexpr int CH = 64;       // scan chunks
static constexpr int L  = T / CH;   // 128 steps/chunk

// ---- async global -> LDS (16B per lane, wave-uniform LDS base) ----
__device__ __forceinline__ void g2lds16(const void* g, void* l) {
  __builtin_amdgcn_global_load_lds(
      (const __attribute__((address_space(1))) unsigned int*)g,
      (__attribute__((address_space(3))) unsigned int*)l, 16, 0, 0);
}

// ---- simple f32 -> bf16 cast (weights) ----
__global__ __launch_bounds__(256) void cast_f32_bf16(const float* __restrict__ in,
                                                     __bf16* __restrict__ out, int n4) {
  int i = blockIdx.x * 256 + threadIdx.x;
  if (i >= n4) return;
  const f32x4 v = *(const f32x4*)(in + (size_t)i * 4);
  bf16x4 o;
  o[0] = (__bf16)v[0]; o[1] = (__bf16)v[1]; o[2] = (__bf16)v[2]; o[3] = (__bf16)v[3];
  *(bf16x4*)(out + (size_t)i * 4) = o;
}

// ---- residual causal depthwise conv + cast to bf16 ----
__global__ __launch_bounds__(256) void conv_residual_cast(const float* __restrict__ x,
                                                          const float* __restrict__ cw,
                                                          const float* __restrict__ cb,
                                                          __bf16* __restrict__ xc) {
  const size_t i4 = (size_t)blockIdx.x * 256 + threadIdx.x;
  const size_t v  = i4 * 4;                    // element index into [B,T,H]
  const int    h  = (int)(v & (size_t)(H - 1));
  const size_t bt = v >> 10;                   // /H
  const int    t  = (int)(bt & (size_t)(T - 1));
  f32x4 acc = *(const f32x4*)(cb + h);
  const f32x4 xv = *(const f32x4*)(x + v);
#pragma unroll
  for (int i = 0; i < 4; ++i) {
    const int tt = t - 3 + i;
    if (tt >= 0) {
      const f32x4 xi = *(const f32x4*)(x + (bt - 3 + i) * H + h);
      const f32x4 wi = *(const f32x4*)(cw + i * H + h);
      acc += wi * xi;
    }
  }
  acc += xv;  // residual
  bf16x4 o;
  o[0] = (__bf16)acc[0]; o[1] = (__bf16)acc[1]; o[2] = (__bf16)acc[2]; o[3] = (__bf16)acc[3];
  *(bf16x4*)(xc + v) = o;
}

// ============================================================================
// 256x256 8-phase GEMM: C[M,N] = A[M,K] @ B[N,K]^T, bf16 in, fp32 acc.
// 512 threads = 8 waves (2M x 4N), per-wave 128x64 output via 16x16x32 MFMA.
// BK=64, double-buffered LDS (128 KiB), XOR-swizzled chunks (chunk ^= row&7)
// applied on the pre-swizzled GLOBAL source (LDS dest is wave-contiguous).
//
// Zigzag quadrant order with fragment register reuse (24 ds_read_b128 / tile
// instead of 48 -- LDS read traffic was the round-1 ceiling):
//   ph1 (0,0): read A02[8] + Bev[4]   MFMA afA x bfE
//   ph2 (0,1): read Bod[4]            MFMA afA x bfO   (afA reused)
//   ph3 (1,1): read A13[8]            MFMA afB x bfO   (bfO reused)
//   ph4 (1,0): no reads               MFMA afB x bfE   (bfE held from ph1)
// Stage stream (2 x global_load_lds per phase) and vmcnt(4)-at-ph4 invariant
// unchanged from round 1 (region death times only got earlier):
//   tile t+1: Bev@ph3(t-1), A02@ph4(t-1)  [into cur's dead slots]
//             A13@ph1(t),   Bod@ph2(t)    [into nxt]
// At each ph4 checkpoint: 12 in flight, vmcnt(4) -> all of tile t+1 landed.
// ============================================================================

#define STG_A(buf, k0, ro) g2lds16(aBase + (size_t)(r + (ro)) * K + (k0), \
                                   &sA[buf][(w8 + (ro)) * 64])
#define STG_B(buf, k0, ro) g2lds16(bBase + (size_t)(rB + (ro)) * K + (k0), \
                                   &sB[buf][(w8B + (ro)) * 64])
#define STAGE_A02(buf, kt) do { const int k0_ = (kt) * 64; STG_A(buf, k0_, 0);  STG_A(buf, k0_, 128); } while (0)
#define STAGE_A13(buf, kt) do { const int k0_ = (kt) * 64; STG_A(buf, k0_, 64); STG_A(buf, k0_, 192); } while (0)
#define STAGE_BEV(buf, kt) do { const int k0_ = (kt) * 64; STG_B(buf, k0_, 0);  STG_B(buf, k0_, 128); } while (0)
#define STAGE_BOD(buf, kt) do { const int k0_ = (kt) * 64; STG_B(buf, k0_, 32); STG_B(buf, k0_, 160); } while (0)

#define RD_A(dst, MQ) do {                                                           \
    _Pragma("unroll") for (int i_ = 0; i_ < 4; ++i_) {                               \
      const int rt_ = aRowBase + (MQ) * 64 + i_ * 16;                                \
      _Pragma("unroll") for (int ks_ = 0; ks_ < 2; ++ks_)                            \
        dst[i_][ks_] = *(const bf16x8*)&sAc[rt_ * 64 + (((ks_ * 4 + kg) ^ (rt_ & 7)) * 8)]; \
    } } while (0)

#define RD_B(dst, NQ) do {                                                           \
    _Pragma("unroll") for (int j_ = 0; j_ < 2; ++j_) {                               \
      const int rt_ = bRowBase + (NQ) * 32 + j_ * 16;                                \
      _Pragma("unroll") for (int ks_ = 0; ks_ < 2; ++ks_)                            \
        dst[j_][ks_] = *(const bf16x8*)&sBc[rt_ * 64 + (((ks_ * 4 + kg) ^ (rt_ & 7)) * 8)]; \
    } } while (0)

#define MMA(AF, BF, MQ, NQ) do {                                                     \
    asm volatile("s_barrier" ::: "memory");                                          \
    asm volatile("s_waitcnt lgkmcnt(0)" ::: "memory");                               \
    __builtin_amdgcn_s_setprio(1);                                                   \
    _Pragma("unroll") for (int i_ = 0; i_ < 4; ++i_)                                 \
      _Pragma("unroll") for (int j_ = 0; j_ < 2; ++j_)                               \
        _Pragma("unroll") for (int ks_ = 0; ks_ < 2; ++ks_)                          \
          acc[(MQ) * 4 + i_][(NQ) * 2 + j_] = __builtin_amdgcn_mfma_f32_16x16x32_bf16( \
              AF[i_][ks_], BF[j_][ks_], acc[(MQ) * 4 + i_][(NQ) * 2 + j_], 0, 0, 0); \
    __builtin_amdgcn_s_setprio(0);                                                   \
  } while (0)

template <typename OUT_T>
__global__ __launch_bounds__(512, 2) void gemm256(const __bf16* __restrict__ A,
                                                  const __bf16* __restrict__ Bm,
                                                  OUT_T* __restrict__ C,
                                                  int M, int N, int K, int nbx) {
  __shared__ __align__(16) __bf16 sA[2][256 * 64];
  __shared__ __align__(16) __bf16 sB[2][256 * 64];
  const int tid  = threadIdx.x;
  const int wave = tid >> 6;
  const int lane = tid & 63;
  const int wm = wave >> 2;  // 0..1
  const int wn = wave & 3;   // 0..3

  // T1: bijective XCD swizzle (both launches have nwg % 8 == 0)
  const int nwg = gridDim.x;
  int wg = blockIdx.x;
  wg = (wg & 7) * (nwg >> 3) + (wg >> 3);
  const int bm0 = (wg / nbx) * 256;
  const int bn0 = (wg % nbx) * 256;

  const int NT = K >> 6;  // K-tiles of 64

  // ---- staging geometry (per-thread constants) ----
  const int r   = tid >> 3;              // 0..63 row-in-round
  const int sgc = (tid & 7) ^ (r & 7);   // pre-swizzled source chunk
  const int rB  = r + (r & 32);          // B row pattern {0-31, 64-95}
  const int w8  = wave * 8;              // wave-uniform LDS row base
  const int w8B = w8 + (w8 & 32);
  const __bf16* aBase = A  + (size_t)bm0 * K + sgc * 8;
  const __bf16* bBase = Bm + (size_t)bn0 * K + sgc * 8;

  // ---- fragment-read geometry ----
  const int l15 = lane & 15;
  const int kg  = lane >> 4;             // k-group 0..3 (8 elems each)
  const int aRowBase = wm * 128 + l15;
  const int bRowBase = wn * 64 + l15;

  f32x4 acc[8][4] = {};

  // ---- prologue: stream positions ph3(-2)..ph4(-1) ----
  STAGE_BEV(0, 0);
  STAGE_A02(0, 0);
  STAGE_A13(0, 0);
  STAGE_BOD(0, 0);
  {
    const int k1 = NT > 1 ? 1 : 0;
    STAGE_BEV(1, k1);
    STAGE_A02(1, k1);
  }
  asm volatile("s_waitcnt vmcnt(4)" ::: "memory");  // tile 0 fully landed
  asm volatile("s_barrier" ::: "memory");

  for (int kt = 0; kt < NT; ++kt) {
    const int cur = kt & 1, nxt = cur ^ 1;
    const int kt1 = (kt + 1 < NT) ? kt + 1 : NT - 1;
    const int kt2 = (kt + 2 < NT) ? kt + 2 : NT - 1;
    const __bf16* sAc = sA[cur];
    const __bf16* sBc = sB[cur];
    bf16x8 afA[4][2], afB[4][2], bfE[2][2], bfO[2][2];

    // ---- phase 1: (0,0) ----
    RD_A(afA, 0);
    RD_B(bfE, 0);
    STAGE_A13(nxt, kt1);
    asm volatile("s_waitcnt lgkmcnt(8)" ::: "memory");
    MMA(afA, bfE, 0, 0);
    asm volatile("s_barrier" ::: "memory");
    // ---- phase 2: (0,1) ----
    RD_B(bfO, 1);
    STAGE_BOD(nxt, kt1);
    MMA(afA, bfO, 0, 1);
    asm volatile("s_barrier" ::: "memory");
    // ---- phase 3: (1,1) ----
    RD_A(afB, 1);
    STAGE_BEV(cur, kt2);
    MMA(afB, bfO, 1, 1);
    asm volatile("s_barrier" ::: "memory");
    // ---- phase 4: (1,0), no ds_reads ----
    STAGE_A02(cur, kt2);
    MMA(afB, bfE, 1, 0);
    asm volatile("s_waitcnt vmcnt(4)" ::: "memory");
    asm volatile("s_barrier" ::: "memory");
  }

  // ---- epilogue: 16x16 C/D layout: col = lane&15, row = (lane>>4)*4 + reg ----
  const int orow0 = bm0 + wm * 128 + kg * 4;
  const int ocol0 = bn0 + wn * 64 + l15;
#pragma unroll
  for (int mi = 0; mi < 8; ++mi)
#pragma unroll
    for (int nj = 0; nj < 4; ++nj) {
      const size_t rbase = (size_t)(orow0 + mi * 16);
#pragma unroll
      for (int rr = 0; rr < 4; ++rr)
        C[(rbase + rr) * N + (ocol0 + nj * 16)] = (OUT_T)acc[mi][nj][rr];
    }
}

// ---- scan pass 1: per-(b, chunk, r) aggregate (A,B): h_end = A*h_start + B ----
// vectorized: 4 consecutive r per thread (bf16x4 loads, f32x4 agg stores)
__global__ __launch_bounds__(256) void scan_pass1(const __bf16* __restrict__ zh,
                                                  float* __restrict__ aggA,
                                                  float* __restrict__ aggB) {
  const int r = (blockIdx.x * 256 + threadIdx.x) * 4;
  const int c = blockIdx.y;
  const int b = blockIdx.z;
  size_t base = ((size_t)b * T + (size_t)c * L) * N1 + r;
  float Aacc[4] = {1.f, 1.f, 1.f, 1.f};
  float Bacc[4] = {0.f, 0.f, 0.f, 0.f};
#pragma unroll 4
  for (int t = 0; t < L; ++t) {
    const bf16x4 s4 = *(const bf16x4*)(zh + base);
    const bf16x4 h4 = *(const bf16x4*)(zh + base + R);
    base += N1;
#pragma unroll
    for (int j = 0; j < 4; ++j) {
      const float z = 1.f / (1.f + __expf(-(float)s4[j]));
      const float a = 1.f - z;
      Bacc[j] = a * Bacc[j] + z * (float)h4[j];
      Aacc[j] *= a;
    }
  }
  const size_t o = ((size_t)b * CH + c) * R + r;
  *(f32x4*)(aggA + o) = f32x4{Aacc[0], Aacc[1], Aacc[2], Aacc[3]};
  *(f32x4*)(aggB + o) = f32x4{Bacc[0], Bacc[1], Bacc[2], Bacc[3]};
}

// ---- scan pass 2: scan the 64 chunk aggregates per (b,r); write carry-in per chunk ----
__global__ __launch_bounds__(256) void scan_pass2(const float* __restrict__ aggA,
                                                  const float* __restrict__ aggB,
                                                  float* __restrict__ carry) {
  const int idx = blockIdx.x * 256 + threadIdx.x;  // b*R + r
  const int b = idx >> 10;
  const int r = idx & (R - 1);
  float h = 0.f;
#pragma unroll 8
  for (int c = 0; c < CH; ++c) {
    const size_t o = ((size_t)b * CH + c) * R + r;
    carry[o] = h;
    h = aggA[o] * h + aggB[o];
  }
}

// ---- scan pass 3: apply carry, recompute gates, emit h_o (bf16) ----
// vectorized: 4 consecutive r per thread
__global__ __launch_bounds__(256) void scan_pass3(const __bf16* __restrict__ zh,
                                                  const float* __restrict__ carry,
                                                  __bf16* __restrict__ ho) {
  const int r = (blockIdx.x * 256 + threadIdx.x) * 4;
  const int c = blockIdx.y;
  const int b = blockIdx.z;
  size_t base  = ((size_t)b * T + (size_t)c * L) * N1 + r;
  size_t obase = ((size_t)b * T + (size_t)c * L) * R + r;
  float h[4];
  const f32x4 cv = *(const f32x4*)(carry + ((size_t)b * CH + c) * R + r);
  h[0] = cv[0]; h[1] = cv[1]; h[2] = cv[2]; h[3] = cv[3];
#pragma unroll 4
  for (int t = 0; t < L; ++t) {
    const bf16x4 s4 = *(const bf16x4*)(zh + base);
    const bf16x4 h4 = *(const bf16x4*)(zh + base + R);
    base += N1;
    bf16x4 o;
#pragma unroll
    for (int j = 0; j < 4; ++j) {
      const float z = 1.f / (1.f + __expf(-(float)s4[j]));
      h[j] = (1.f - z) * h[j] + z * (float)h4[j];
      o[j] = (__bf16)h[j];
    }
    *(bf16x4*)(ho + obase) = o;
    obase += R;
  }
}

extern "C" void kernel_launch(void* const* d_in, const int* in_sizes, int n_in,
                              void* d_out, int out_size, void* d_ws, size_t ws_size,
                              hipStream_t stream) {
  const float* x      = (const float*)d_in[0];
  const float* w_zh   = (const float*)d_in[1];
  const float* w_out  = (const float*)d_in[2];
  const float* conv_w = (const float*)d_in[3];
  const float* conv_b = (const float*)d_in[4];
  float* out = (float*)d_out;

  char* ws = (char*)d_ws;
  size_t off = 0;
  __bf16* wzh_b  = (__bf16*)(ws + off); off += (size_t)N1 * H * 2;        // 4 MiB
  __bf16* wout_b = (__bf16*)(ws + off); off += (size_t)H * R * 2;         // 2 MiB
  __bf16* xc     = (__bf16*)(ws + off); off += (size_t)BT * H * 2;        // 64 MiB
  __bf16* zh     = (__bf16*)(ws + off); off += (size_t)BT * N1 * 2;       // 128 MiB
  float*  aggA   = (float*)(ws + off);  off += (size_t)Bb * CH * R * 4;   // 1 MiB
  float*  aggB   = (float*)(ws + off);  off += (size_t)Bb * CH * R * 4;   // 1 MiB
  float*  carry  = (float*)(ws + off);  off += (size_t)Bb * CH * R * 4;   // 1 MiB
  __bf16* ho = xc;  // alias: xc is dead after GEMM1

  cast_f32_bf16<<<(N1 * H / 4 + 255) / 256, 256, 0, stream>>>(w_zh, wzh_b, N1 * H / 4);
  cast_f32_bf16<<<(H * R / 4 + 255) / 256, 256, 0, stream>>>(w_out, wout_b, H * R / 4);
  conv_residual_cast<<<BT * H / 4 / 256, 256, 0, stream>>>(x, conv_w, conv_b, xc);
  // GEMM1: [32768,1024] @ [2048,1024]^T -> zh ; grid 128*8 = 1024 blocks
  gemm256<__bf16><<<(BT / 256) * (N1 / 256), 512, 0, stream>>>(xc, wzh_b, zh, BT, N1, H, N1 / 256);
  scan_pass1<<<dim3(R / 4 / 256, CH, Bb), 256, 0, stream>>>(zh, aggA, aggB);
  scan_pass2<<<Bb * R / 256, 256, 0, stream>>>(aggA, aggB, carry);
  scan_pass3<<<dim3(R / 4 / 256, CH, Bb), 256, 0, stream>>>(zh, carry, ho);
  // GEMM2: [32768,1024] @ [1024,1024]^T -> out ; grid 128*4 = 512 blocks
  gemm256<float><<<(BT / 256) * (H / 256), 512, 0, stream>>>(ho, wout_b, out, BT, H, R, H / 256);
}

// Round 3
// 568.757 us; speedup vs baseline: 1.0830x; 1.0830x over previous
//
#include <hip/hip_runtime.h>

typedef __bf16 bf16x8 __attribute__((ext_vector_type(8)));
typedef __bf16 bf16x4 __attribute__((ext_vector_type(4)));
typedef float  f32x4  __attribute__((ext_vector_type(4)));

static constexpr int Bb = 4, T = 8192, H = 1024, R = 1024;
static constexpr int BT = Bb * T;   // 32768 rows
static constexpr int N1 = 2 * R;    // 2048 (z|h columns)
static constexpr int CH = 128;      // scan chunks (128 -> 512 blocks, 8 waves/CU)
static constexpr int L  = T / CH;   // 64 steps/chunk

// ---- async global -> LDS (16B per lane, wave-uniform LDS base) ----
__device__ __forceinline__ void g2lds16(const void* g, void* l) {
  __builtin_amdgcn_global_load_lds(
      (const __attribute__((address_space(1))) unsigned int*)g,
      (__attribute__((address_space(3))) unsigned int*)l, 16, 0, 0);
}

// ---- simple f32 -> bf16 cast (weights) ----
__global__ __launch_bounds__(256) void cast_f32_bf16(const float* __restrict__ in,
                                                     __bf16* __restrict__ out, int n4) {
  int i = blockIdx.x * 256 + threadIdx.x;
  if (i >= n4) return;
  const f32x4 v = *(const f32x4*)(in + (size_t)i * 4);
  bf16x4 o;
  o[0] = (__bf16)v[0]; o[1] = (__bf16)v[1]; o[2] = (__bf16)v[2]; o[3] = (__bf16)v[3];
  *(bf16x4*)(out + (size_t)i * 4) = o;
}

// ---- residual causal depthwise conv + cast to bf16 ----
__global__ __launch_bounds__(256) void conv_residual_cast(const float* __restrict__ x,
                                                          const float* __restrict__ cw,
                                                          const float* __restrict__ cb,
                                                          __bf16* __restrict__ xc) {
  const size_t i4 = (size_t)blockIdx.x * 256 + threadIdx.x;
  const size_t v  = i4 * 4;                    // element index into [B,T,H]
  const int    h  = (int)(v & (size_t)(H - 1));
  const size_t bt = v >> 10;                   // /H
  const int    t  = (int)(bt & (size_t)(T - 1));
  f32x4 acc = *(const f32x4*)(cb + h);
  const f32x4 xv = *(const f32x4*)(x + v);
#pragma unroll
  for (int i = 0; i < 4; ++i) {
    const int tt = t - 3 + i;
    if (tt >= 0) {
      const f32x4 xi = *(const f32x4*)(x + (bt - 3 + i) * H + h);
      const f32x4 wi = *(const f32x4*)(cw + i * H + h);
      acc += wi * xi;
    }
  }
  acc += xv;  // residual
  bf16x4 o;
  o[0] = (__bf16)acc[0]; o[1] = (__bf16)acc[1]; o[2] = (__bf16)acc[2]; o[3] = (__bf16)acc[3];
  *(bf16x4*)(xc + v) = o;
}

// ============================================================================
// 256x256 GEMM with CROSS-PHASE fragment prefetch: C = A[M,K] @ B[N,K]^T.
// 512 threads = 8 waves (2M x 4N), per-wave 128x64 via 16x16x32 MFMA, BK=64,
// double-buffered LDS (128 KiB), chunk-XOR swizzle on pre-swizzled global src.
//
// Round-2 lesson: {read -> lgkmcnt(0) -> MFMA} per phase serializes LDS and
// MFMA pipes (34% MfmaUtil ceiling). Now phase p reads fragments for phase
// p+1; MFMA consumes registers read one phase earlier; the compiler emits
// counted lgkmcnt waits, so LDS service overlaps the MFMA burst.
//   ph1: rd bfO (cur Bod)      stage A13(nxt,kt1)  MFMA afA x bfE (0,0)
//   ph2: rd afB (cur A13)      stage BOD(nxt,kt1)  MFMA afA x bfO (0,1)  vmcnt(4)
//   ph3: rd afA (nxt A02,kt1)  stage BEV(cur,kt2)  MFMA afB x bfO (1,1)
//   ph4:                       stage A02(cur,kt2)  MFMA afB x bfE (1,0)
//        then rd bfE (nxt Bev,kt1), vmcnt(4)
// vmcnt(4)@ph2-end lands Bev/A02(kt+1) before ph3/ph4 nxt-buffer reads;
// vmcnt(4)@ph4-end lands A13/Bod(kt+1) before next tile's ph1/ph2 reads.
// Each cross-wave LDS read is behind a {per-wave vmcnt -> s_barrier} pair.
// WAR (stage overwriting a region vs last reader) all have >=1 barrier margin.
// ============================================================================

#define STG_A(buf, k0, ro) g2lds16(aBase + (size_t)(r + (ro)) * K + (k0), \
                                   &sA[buf][(w8 + (ro)) * 64])
#define STG_B(buf, k0, ro) g2lds16(bBase + (size_t)(rB + (ro)) * K + (k0), \
                                   &sB[buf][(w8B + (ro)) * 64])
#define STAGE_A02(buf, kt) do { const int k0_ = (kt) * 64; STG_A(buf, k0_, 0);  STG_A(buf, k0_, 128); } while (0)
#define STAGE_A13(buf, kt) do { const int k0_ = (kt) * 64; STG_A(buf, k0_, 64); STG_A(buf, k0_, 192); } while (0)
#define STAGE_BEV(buf, kt) do { const int k0_ = (kt) * 64; STG_B(buf, k0_, 0);  STG_B(buf, k0_, 128); } while (0)
#define STAGE_BOD(buf, kt) do { const int k0_ = (kt) * 64; STG_B(buf, k0_, 32); STG_B(buf, k0_, 160); } while (0)

#define RD_A(dst, MQ, SRC) do {                                                      \
    _Pragma("unroll") for (int i_ = 0; i_ < 4; ++i_) {                               \
      const int rt_ = aRowBase + (MQ) * 64 + i_ * 16;                                \
      _Pragma("unroll") for (int ks_ = 0; ks_ < 2; ++ks_)                            \
        dst[i_][ks_] = *(const bf16x8*)&(SRC)[rt_ * 64 + (((ks_ * 4 + kg) ^ (rt_ & 7)) * 8)]; \
    } } while (0)

#define RD_B(dst, NQ, SRC) do {                                                      \
    _Pragma("unroll") for (int j_ = 0; j_ < 2; ++j_) {                               \
      const int rt_ = bRowBase + (NQ) * 32 + j_ * 16;                                \
      _Pragma("unroll") for (int ks_ = 0; ks_ < 2; ++ks_)                            \
        dst[j_][ks_] = *(const bf16x8*)&(SRC)[rt_ * 64 + (((ks_ * 4 + kg) ^ (rt_ & 7)) * 8)]; \
    } } while (0)

#define MFMA_CL(AF, BF, MQ, NQ) do {                                                 \
    __builtin_amdgcn_s_setprio(1);                                                   \
    _Pragma("unroll") for (int i_ = 0; i_ < 4; ++i_)                                 \
      _Pragma("unroll") for (int j_ = 0; j_ < 2; ++j_)                               \
        _Pragma("unroll") for (int ks_ = 0; ks_ < 2; ++ks_)                          \
          acc[(MQ) * 4 + i_][(NQ) * 2 + j_] = __builtin_amdgcn_mfma_f32_16x16x32_bf16( \
              AF[i_][ks_], BF[j_][ks_], acc[(MQ) * 4 + i_][(NQ) * 2 + j_], 0, 0, 0); \
    __builtin_amdgcn_s_setprio(0);                                                   \
  } while (0)

#define SB0 __builtin_amdgcn_sched_barrier(0)
#define BARRIER asm volatile("s_barrier" ::: "memory")
#define VMCNT4 asm volatile("s_waitcnt vmcnt(4)" ::: "memory")

template <typename OUT_T>
__global__ __launch_bounds__(512, 2) void gemm256(const __bf16* __restrict__ A,
                                                  const __bf16* __restrict__ Bm,
                                                  OUT_T* __restrict__ C,
                                                  int M, int N, int K, int nbx) {
  __shared__ __align__(16) __bf16 sA[2][256 * 64];
  __shared__ __align__(16) __bf16 sB[2][256 * 64];
  const int tid  = threadIdx.x;
  const int wave = tid >> 6;
  const int lane = tid & 63;
  const int wm = wave >> 2;  // 0..1
  const int wn = wave & 3;   // 0..3

  // T1: bijective XCD swizzle (both launches have nwg % 8 == 0)
  const int nwg = gridDim.x;
  int wg = blockIdx.x;
  wg = (wg & 7) * (nwg >> 3) + (wg >> 3);
  const int bm0 = (wg / nbx) * 256;
  const int bn0 = (wg % nbx) * 256;

  const int NT = K >> 6;  // K-tiles of 64

  // ---- staging geometry (per-thread constants) ----
  const int r   = tid >> 3;              // 0..63 row-in-round
  const int sgc = (tid & 7) ^ (r & 7);   // pre-swizzled source chunk
  const int rB  = r + (r & 32);          // B row pattern {0-31, 64-95}
  const int w8  = wave * 8;              // wave-uniform LDS row base
  const int w8B = w8 + (w8 & 32);
  const __bf16* aBase = A  + (size_t)bm0 * K + sgc * 8;
  const __bf16* bBase = Bm + (size_t)bn0 * K + sgc * 8;

  // ---- fragment-read geometry ----
  const int l15 = lane & 15;
  const int kg  = lane >> 4;             // k-group 0..3 (8 elems each)
  const int aRowBase = wm * 128 + l15;
  const int bRowBase = wn * 64 + l15;

  f32x4 acc[8][4] = {};
  bf16x8 afA[4][2], afB[4][2], bfE[2][2], bfO[2][2];

  // ---- prologue: tile0 full + tile1 Bev/A02 in flight ----
  STAGE_BEV(0, 0);
  STAGE_A02(0, 0);
  STAGE_A13(0, 0);
  STAGE_BOD(0, 0);
  {
    const int k1 = NT > 1 ? 1 : 0;
    STAGE_BEV(1, k1);
    STAGE_A02(1, k1);
  }
  VMCNT4;   // tile 0 fully landed; Bev/A02(1) still in flight
  BARRIER;
  RD_A(afA, 0, sA[0]);   // tile-0 ph1 fragments
  RD_B(bfE, 0, sB[0]);

  for (int kt = 0; kt < NT; ++kt) {
    const int cur = kt & 1, nxt = cur ^ 1;
    const int kt1 = (kt + 1 < NT) ? kt + 1 : NT - 1;
    const int kt2 = (kt + 2 < NT) ? kt + 2 : NT - 1;
    const __bf16* sAc = sA[cur];
    const __bf16* sBc = sB[cur];
    const __bf16* sAn = sA[nxt];
    const __bf16* sBn = sB[nxt];

    // ---- ph1: MFMA(0,0); prefetch bfO for ph2 ----
    RD_B(bfO, 1, sBc);
    STAGE_A13(nxt, kt1);
    SB0;
    MFMA_CL(afA, bfE, 0, 0);
    BARRIER;
    // ---- ph2: MFMA(0,1); prefetch afB for ph3 ----
    RD_A(afB, 1, sAc);
    STAGE_BOD(nxt, kt1);
    SB0;
    MFMA_CL(afA, bfO, 0, 1);
    VMCNT4;   // Bev(kt+1), A02(kt+1) landed (gates ph3/ph4 nxt reads)
    BARRIER;
    // ---- ph3: MFMA(1,1); prefetch afA (next tile) ----
    RD_A(afA, 0, sAn);
    STAGE_BEV(cur, kt2);
    SB0;
    MFMA_CL(afB, bfO, 1, 1);
    BARRIER;
    // ---- ph4: MFMA(1,0); then prefetch bfE (next tile) ----
    STAGE_A02(cur, kt2);
    SB0;
    MFMA_CL(afB, bfE, 1, 0);
    SB0;
    RD_B(bfE, 0, sBn);
    VMCNT4;   // A13(kt+1), Bod(kt+1) landed (gates next ph1/ph2 cur reads)
    BARRIER;
  }

  // ---- epilogue: 16x16 C/D layout: col = lane&15, row = (lane>>4)*4 + reg ----
  const int orow0 = bm0 + wm * 128 + kg * 4;
  const int ocol0 = bn0 + wn * 64 + l15;
#pragma unroll
  for (int mi = 0; mi < 8; ++mi)
#pragma unroll
    for (int nj = 0; nj < 4; ++nj) {
      const size_t rbase = (size_t)(orow0 + mi * 16);
#pragma unroll
      for (int rr = 0; rr < 4; ++rr)
        C[(rbase + rr) * N + (ocol0 + nj * 16)] = (OUT_T)acc[mi][nj][rr];
    }
}

// ---- scan pass 1: per-(b, chunk, r) aggregate (A,B): h_end = A*h_start + B ----
// vectorized: 4 consecutive r per thread (bf16x4 loads, f32x4 agg stores)
__global__ __launch_bounds__(256) void scan_pass1(const __bf16* __restrict__ zh,
                                                  float* __restrict__ aggA,
                                                  float* __restrict__ aggB) {
  const int r = (blockIdx.x * 256 + threadIdx.x) * 4;
  const int c = blockIdx.y;
  const int b = blockIdx.z;
  size_t base = ((size_t)b * T + (size_t)c * L) * N1 + r;
  float Aacc[4] = {1.f, 1.f, 1.f, 1.f};
  float Bacc[4] = {0.f, 0.f, 0.f, 0.f};
#pragma unroll 4
  for (int t = 0; t < L; ++t) {
    const bf16x4 s4 = *(const bf16x4*)(zh + base);
    const bf16x4 h4 = *(const bf16x4*)(zh + base + R);
    base += N1;
#pragma unroll
    for (int j = 0; j < 4; ++j) {
      const float z = 1.f / (1.f + __expf(-(float)s4[j]));
      const float a = 1.f - z;
      Bacc[j] = a * Bacc[j] + z * (float)h4[j];
      Aacc[j] *= a;
    }
  }
  const size_t o = ((size_t)b * CH + c) * R + r;
  *(f32x4*)(aggA + o) = f32x4{Aacc[0], Aacc[1], Aacc[2], Aacc[3]};
  *(f32x4*)(aggB + o) = f32x4{Bacc[0], Bacc[1], Bacc[2], Bacc[3]};
}

// ---- scan pass 2: scan the CH chunk aggregates per (b,r); write carry-in ----
__global__ __launch_bounds__(256) void scan_pass2(const float* __restrict__ aggA,
                                                  const float* __restrict__ aggB,
                                                  float* __restrict__ carry) {
  const int idx = blockIdx.x * 256 + threadIdx.x;  // b*R + r
  const int b = idx >> 10;
  const int r = idx & (R - 1);
  float h = 0.f;
#pragma unroll 8
  for (int c = 0; c < CH; ++c) {
    const size_t o = ((size_t)b * CH + c) * R + r;
    carry[o] = h;
    h = aggA[o] * h + aggB[o];
  }
}

// ---- scan pass 3: apply carry, recompute gates, emit h_o (bf16) ----
// vectorized: 4 consecutive r per thread
__global__ __launch_bounds__(256) void scan_pass3(const __bf16* __restrict__ zh,
                                                  const float* __restrict__ carry,
                                                  __bf16* __restrict__ ho) {
  const int r = (blockIdx.x * 256 + threadIdx.x) * 4;
  const int c = blockIdx.y;
  const int b = blockIdx.z;
  size_t base  = ((size_t)b * T + (size_t)c * L) * N1 + r;
  size_t obase = ((size_t)b * T + (size_t)c * L) * R + r;
  float h[4];
  const f32x4 cv = *(const f32x4*)(carry + ((size_t)b * CH + c) * R + r);
  h[0] = cv[0]; h[1] = cv[1]; h[2] = cv[2]; h[3] = cv[3];
#pragma unroll 4
  for (int t = 0; t < L; ++t) {
    const bf16x4 s4 = *(const bf16x4*)(zh + base);
    const bf16x4 h4 = *(const bf16x4*)(zh + base + R);
    base += N1;
    bf16x4 o;
#pragma unroll
    for (int j = 0; j < 4; ++j) {
      const float z = 1.f / (1.f + __expf(-(float)s4[j]));
      h[j] = (1.f - z) * h[j] + z * (float)h4[j];
      o[j] = (__bf16)h[j];
    }
    *(bf16x4*)(ho + obase) = o;
    obase += R;
  }
}

extern "C" void kernel_launch(void* const* d_in, const int* in_sizes, int n_in,
                              void* d_out, int out_size, void* d_ws, size_t ws_size,
                              hipStream_t stream) {
  const float* x      = (const float*)d_in[0];
  const float* w_zh   = (const float*)d_in[1];
  const float* w_out  = (const float*)d_in[2];
  const float* conv_w = (const float*)d_in[3];
  const float* conv_b = (const float*)d_in[4];
  float* out = (float*)d_out;

  char* ws = (char*)d_ws;
  size_t off = 0;
  __bf16* wzh_b  = (__bf16*)(ws + off); off += (size_t)N1 * H * 2;        // 4 MiB
  __bf16* wout_b = (__bf16*)(ws + off); off += (size_t)H * R * 2;         // 2 MiB
  __bf16* xc     = (__bf16*)(ws + off); off += (size_t)BT * H * 2;        // 64 MiB
  __bf16* zh     = (__bf16*)(ws + off); off += (size_t)BT * N1 * 2;       // 128 MiB
  float*  carry  = (float*)(ws + off);  off += (size_t)Bb * CH * R * 4;   // 2 MiB
  // aggA/aggB alias the dead wzh_b region (4 MiB, dead after GEMM1)
  float*  aggA   = (float*)wzh_b;                       // 2 MiB
  float*  aggB   = (float*)((char*)wzh_b + (size_t)Bb * CH * R * 4);  // 2 MiB
  __bf16* ho = xc;  // alias: xc is dead after GEMM1

  cast_f32_bf16<<<(N1 * H / 4 + 255) / 256, 256, 0, stream>>>(w_zh, wzh_b, N1 * H / 4);
  cast_f32_bf16<<<(H * R / 4 + 255) / 256, 256, 0, stream>>>(w_out, wout_b, H * R / 4);
  conv_residual_cast<<<BT * H / 4 / 256, 256, 0, stream>>>(x, conv_w, conv_b, xc);
  // GEMM1: [32768,1024] @ [2048,1024]^T -> zh ; grid 128*8 = 1024 blocks
  gemm256<__bf16><<<(BT / 256) * (N1 / 256), 512, 0, stream>>>(xc, wzh_b, zh, BT, N1, H, N1 / 256);
  scan_pass1<<<dim3(R / 4 / 256, CH, Bb), 256, 0, stream>>>(zh, aggA, aggB);
  scan_pass2<<<Bb * R / 256, 256, 0, stream>>>(aggA, aggB, carry);
  scan_pass3<<<dim3(R / 4 / 256, CH, Bb), 256, 0, stream>>>(zh, carry, ho);
  // GEMM2: [32768,1024] @ [1024,1024]^T -> out ; grid 128*4 = 512 blocks
  gemm256<float><<<(BT / 256) * (H / 256), 512, 0, stream>>>(ho, wout_b, out, BT, H, R, H / 256);
}

// Round 4
// 552.704 us; speedup vs baseline: 1.1145x; 1.0290x over previous
//
#include <hip/hip_runtime.h>

typedef __bf16 bf16x8 __attribute__((ext_vector_type(8)));
typedef __bf16 bf16x4 __attribute__((ext_vector_type(4)));
typedef float  f32x4  __attribute__((ext_vector_type(4)));
typedef float  f32x16 __attribute__((ext_vector_type(16)));

static constexpr int Bb = 4, T = 8192, H = 1024, R = 1024;
static constexpr int BT = Bb * T;   // 32768 rows
static constexpr int N1 = 2 * R;    // 2048 (z|h columns)
static constexpr int CH = 128;      // scan chunks
static constexpr int L  = T / CH;   // 64 steps/chunk

// ---- async global -> LDS (16B per lane, wave-uniform LDS base) ----
__device__ __forceinline__ void g2lds16(const void* g, void* l) {
  __builtin_amdgcn_global_load_lds(
      (const __attribute__((address_space(1))) unsigned int*)g,
      (__attribute__((address_space(3))) unsigned int*)l, 16, 0, 0);
}

// ---- simple f32 -> bf16 cast (weights) ----
__global__ __launch_bounds__(256) void cast_f32_bf16(const float* __restrict__ in,
                                                     __bf16* __restrict__ out, int n4) {
  int i = blockIdx.x * 256 + threadIdx.x;
  if (i >= n4) return;
  const f32x4 v = *(const f32x4*)(in + (size_t)i * 4);
  bf16x4 o;
  o[0] = (__bf16)v[0]; o[1] = (__bf16)v[1]; o[2] = (__bf16)v[2]; o[3] = (__bf16)v[3];
  *(bf16x4*)(out + (size_t)i * 4) = o;
}

// ---- residual causal depthwise conv + cast to bf16, t-blocked (8 t/thread) ----
// register ring: out[t] = x[t] + cb + w0*x[t-3] + w1*x[t-2] + w2*x[t-1] + w3*x[t]
__global__ __launch_bounds__(256) void conv_residual_cast(const float* __restrict__ x,
                                                          const float* __restrict__ cw,
                                                          const float* __restrict__ cb,
                                                          __bf16* __restrict__ xc) {
  const int h  = threadIdx.x * 4;          // 256 thr * 4 = H
  const int b  = blockIdx.y;
  const int t0 = blockIdx.x * 8;
  const f32x4 w0 = *(const f32x4*)(cw + 0 * H + h);
  const f32x4 w1 = *(const f32x4*)(cw + 1 * H + h);
  const f32x4 w2 = *(const f32x4*)(cw + 2 * H + h);
  const f32x4 w3 = *(const f32x4*)(cw + 3 * H + h);
  const f32x4 bias = *(const f32x4*)(cb + h);
  size_t base = ((size_t)b * T + t0) * H + h;
  f32x4 xm3, xm2, xm1;
  if (t0 >= 3) {
    xm3 = *(const f32x4*)(x + base - 3 * H);
    xm2 = *(const f32x4*)(x + base - 2 * H);
    xm1 = *(const f32x4*)(x + base - 1 * H);
  } else {  // t0 == 0 (t0 is a multiple of 8)
    xm3 = f32x4{0, 0, 0, 0}; xm2 = xm3; xm1 = xm3;
  }
#pragma unroll
  for (int tt = 0; tt < 8; ++tt) {
    const f32x4 x0 = *(const f32x4*)(x + base);
    const f32x4 acc = x0 + bias + w0 * xm3 + w1 * xm2 + w2 * xm1 + w3 * x0;
    bf16x4 o;
    o[0] = (__bf16)acc[0]; o[1] = (__bf16)acc[1]; o[2] = (__bf16)acc[2]; o[3] = (__bf16)acc[3];
    *(bf16x4*)(xc + base) = o;
    xm3 = xm2; xm2 = xm1; xm1 = x0;
    base += H;
  }
}

// ============================================================================
// 256x256 GEMM, cross-phase prefetch, 32x32x16 MFMA fragments (round-0 verified
// layout), manual x2 K-unroll (static LDS buffer indices).
// 512 threads = 8 waves (2M x 4N), per-wave 128x64, BK=64, dbuf LDS 128 KiB,
// chunk-XOR swizzle (chunk ^= row&7) on pre-swizzled global source.
//   ph1: rd bfO (cur Bod)      stage A13(nxt,kt1)  MFMA afA x bfE (0,0)
//   ph2: rd afB (cur A13)      stage BOD(nxt,kt1)  MFMA afA x bfO (0,1)  vmcnt(4)
//   ph3: rd afA (nxt A02,kt1)  stage BEV(cur,kt2)  MFMA afB x bfO (1,1)
//   ph4:                       stage A02(cur,kt2)  MFMA afB x bfE (1,0)
//        then rd bfE (nxt Bev,kt1), vmcnt(4)
// ============================================================================

#define STG_A(buf, k0, ro) g2lds16(aBase + (size_t)(r + (ro)) * K + (k0), \
                                   &sA[buf][(w8 + (ro)) * 64])
#define STG_B(buf, k0, ro) g2lds16(bBase + (size_t)(rB + (ro)) * K + (k0), \
                                   &sB[buf][(w8B + (ro)) * 64])
#define STAGE_A02(buf, kt) do { const int k0_ = (kt) * 64; STG_A(buf, k0_, 0);  STG_A(buf, k0_, 128); } while (0)
#define STAGE_A13(buf, kt) do { const int k0_ = (kt) * 64; STG_A(buf, k0_, 64); STG_A(buf, k0_, 192); } while (0)
#define STAGE_BEV(buf, kt) do { const int k0_ = (kt) * 64; STG_B(buf, k0_, 0);  STG_B(buf, k0_, 128); } while (0)
#define STAGE_BOD(buf, kt) do { const int k0_ = (kt) * 64; STG_B(buf, k0_, 32); STG_B(buf, k0_, 160); } while (0)

// A fragments: dst[m_][ks_], m_ in {0,1} (32-row subtiles within the MQ half)
#define RD_A(dst, MQ, SRC) do {                                                      \
    _Pragma("unroll") for (int m_ = 0; m_ < 2; ++m_) {                               \
      const int rt_ = aRowBase + (MQ) * 64 + m_ * 32;                                \
      _Pragma("unroll") for (int ks_ = 0; ks_ < 4; ++ks_)                            \
        dst[m_][ks_] = *(const bf16x8*)&(SRC)[rt_ * 64 + (((2 * ks_ + kb) ^ (rt_ & 7)) * 8)]; \
    } } while (0)

// B fragments: dst[ks_]
#define RD_B(dst, NQ, SRC) do {                                                      \
    const int rt_ = bRowBase + (NQ) * 32;                                            \
    _Pragma("unroll") for (int ks_ = 0; ks_ < 4; ++ks_)                              \
      dst[ks_] = *(const bf16x8*)&(SRC)[rt_ * 64 + (((2 * ks_ + kb) ^ (rt_ & 7)) * 8)]; \
  } while (0)

#define MFMA_CL(AF, BF, MQ, NQ) do {                                                 \
    __builtin_amdgcn_s_setprio(1);                                                   \
    _Pragma("unroll") for (int ks_ = 0; ks_ < 4; ++ks_)                              \
      _Pragma("unroll") for (int m_ = 0; m_ < 2; ++m_)                               \
        acc[(MQ) * 2 + m_][NQ] = __builtin_amdgcn_mfma_f32_32x32x16_bf16(            \
            AF[m_][ks_], BF[ks_], acc[(MQ) * 2 + m_][NQ], 0, 0, 0);                  \
    __builtin_amdgcn_s_setprio(0);                                                   \
  } while (0)

#define SB0 __builtin_amdgcn_sched_barrier(0)
#define BARRIER asm volatile("s_barrier" ::: "memory")
#define VMCNT4 asm volatile("s_waitcnt vmcnt(4)" ::: "memory")

// one K-tile body; CI/NI are compile-time buffer indices
#define TILE_BODY(KT, CI, NI) do {                                                   \
    const int kt1 = ((KT) + 1 < NT) ? (KT) + 1 : NT - 1;                             \
    const int kt2 = ((KT) + 2 < NT) ? (KT) + 2 : NT - 1;                             \
    /* ph1 */ RD_B(bfO, 1, sB[CI]); STAGE_A13(NI, kt1); SB0;                         \
    MFMA_CL(afA, bfE, 0, 0); BARRIER;                                                \
    /* ph2 */ RD_A(afB, 1, sA[CI]); STAGE_BOD(NI, kt1); SB0;                         \
    MFMA_CL(afA, bfO, 0, 1); VMCNT4; BARRIER;                                        \
    /* ph3 */ RD_A(afA, 0, sA[NI]); STAGE_BEV(CI, kt2); SB0;                         \
    MFMA_CL(afB, bfO, 1, 1); BARRIER;                                                \
    /* ph4 */ STAGE_A02(CI, kt2); SB0;                                               \
    MFMA_CL(afB, bfE, 1, 0); SB0;                                                    \
    RD_B(bfE, 0, sB[NI]); VMCNT4; BARRIER;                                           \
  } while (0)

template <typename OUT_T>
__global__ __launch_bounds__(512, 2) void gemm256(const __bf16* __restrict__ A,
                                                  const __bf16* __restrict__ Bm,
                                                  OUT_T* __restrict__ C,
                                                  int M, int N, int K, int nbx) {
  __shared__ __align__(16) __bf16 sA[2][256 * 64];
  __shared__ __align__(16) __bf16 sB[2][256 * 64];
  const int tid  = threadIdx.x;
  const int wave = tid >> 6;
  const int lane = tid & 63;
  const int wm = wave >> 2;  // 0..1
  const int wn = wave & 3;   // 0..3

  // T1: bijective XCD swizzle (both launches have nwg % 8 == 0)
  const int nwg = gridDim.x;
  int wg = blockIdx.x;
  wg = (wg & 7) * (nwg >> 3) + (wg >> 3);
  const int bm0 = (wg / nbx) * 256;
  const int bn0 = (wg % nbx) * 256;

  const int NT = K >> 6;  // K-tiles of 64 (16 here; even)

  // ---- staging geometry (per-thread constants) ----
  const int r   = tid >> 3;              // 0..63 row-in-round
  const int sgc = (tid & 7) ^ (r & 7);   // pre-swizzled source chunk
  const int rB  = r + (r & 32);          // B row pattern {0-31, 64-95}
  const int w8  = wave * 8;              // wave-uniform LDS row base
  const int w8B = w8 + (w8 & 32);
  const __bf16* aBase = A  + (size_t)bm0 * K + sgc * 8;
  const __bf16* bBase = Bm + (size_t)bn0 * K + sgc * 8;

  // ---- fragment-read geometry (32x32x16) ----
  const int ln = lane & 31;              // row within 32-subtile
  const int kb = lane >> 5;              // k-half 0/1 within a 16-wide k-step
  const int aRowBase = wm * 128 + ln;
  const int bRowBase = wn * 64 + ln;

  f32x16 acc[4][2] = {};
  bf16x8 afA[2][4], afB[2][4], bfE[4], bfO[4];

  // ---- prologue: tile0 full + tile1 Bev/A02 in flight ----
  STAGE_BEV(0, 0);
  STAGE_A02(0, 0);
  STAGE_A13(0, 0);
  STAGE_BOD(0, 0);
  {
    const int k1 = NT > 1 ? 1 : 0;
    STAGE_BEV(1, k1);
    STAGE_A02(1, k1);
  }
  VMCNT4;   // tile 0 fully landed; Bev/A02(1) still in flight
  BARRIER;
  RD_A(afA, 0, sA[0]);   // tile-0 ph1 fragments
  RD_B(bfE, 0, sB[0]);

  for (int kt = 0; kt < NT; kt += 2) {
    TILE_BODY(kt, 0, 1);
    TILE_BODY(kt + 1, 1, 0);
  }

  // ---- epilogue: 32x32 C/D: col = lane&31, row = (reg&3)+8*(reg>>2)+4*(lane>>5)
  const int orow0 = bm0 + wm * 128;
  const int ocol0 = bn0 + wn * 64;
#pragma unroll
  for (int a = 0; a < 4; ++a)
#pragma unroll
    for (int j = 0; j < 2; ++j) {
      const int col = ocol0 + j * 32 + ln;
#pragma unroll
      for (int rr = 0; rr < 16; ++rr) {
        const int row = orow0 + a * 32 + (rr & 3) + 8 * (rr >> 2) + 4 * kb;
        C[(size_t)row * N + col] = (OUT_T)acc[a][j][rr];
      }
    }
}

// ---- scan pass 1: per-(b, chunk, r) aggregate (A,B): h_end = A*h_start + B ----
// vectorized: 4 consecutive r per thread (bf16x4 loads, f32x4 agg stores)
__global__ __launch_bounds__(256) void scan_pass1(const __bf16* __restrict__ zh,
                                                  float* __restrict__ aggA,
                                                  float* __restrict__ aggB) {
  const int r = (blockIdx.x * 256 + threadIdx.x) * 4;
  const int c = blockIdx.y;
  const int b = blockIdx.z;
  size_t base = ((size_t)b * T + (size_t)c * L) * N1 + r;
  float Aacc[4] = {1.f, 1.f, 1.f, 1.f};
  float Bacc[4] = {0.f, 0.f, 0.f, 0.f};
#pragma unroll 4
  for (int t = 0; t < L; ++t) {
    const bf16x4 s4 = *(const bf16x4*)(zh + base);
    const bf16x4 h4 = *(const bf16x4*)(zh + base + R);
    base += N1;
#pragma unroll
    for (int j = 0; j < 4; ++j) {
      const float z = 1.f / (1.f + __expf(-(float)s4[j]));
      const float a = 1.f - z;
      Bacc[j] = a * Bacc[j] + z * (float)h4[j];
      Aacc[j] *= a;
    }
  }
  const size_t o = ((size_t)b * CH + c) * R + r;
  *(f32x4*)(aggA + o) = f32x4{Aacc[0], Aacc[1], Aacc[2], Aacc[3]};
  *(f32x4*)(aggB + o) = f32x4{Bacc[0], Bacc[1], Bacc[2], Bacc[3]};
}

// ---- scan pass 2: scan the CH chunk aggregates per (b,r); write carry-in ----
// 64-thread blocks -> 64 blocks across CUs (was 16)
__global__ __launch_bounds__(64) void scan_pass2(const float* __restrict__ aggA,
                                                 const float* __restrict__ aggB,
                                                 float* __restrict__ carry) {
  const int idx = blockIdx.x * 64 + threadIdx.x;  // b*R + r
  const int b = idx >> 10;
  const int r = idx & (R - 1);
  float h = 0.f;
#pragma unroll 8
  for (int c = 0; c < CH; ++c) {
    const size_t o = ((size_t)b * CH + c) * R + r;
    carry[o] = h;
    h = aggA[o] * h + aggB[o];
  }
}

// ---- scan pass 3: apply carry, recompute gates, emit h_o (bf16) ----
// vectorized: 4 consecutive r per thread
__global__ __launch_bounds__(256) void scan_pass3(const __bf16* __restrict__ zh,
                                                  const float* __restrict__ carry,
                                                  __bf16* __restrict__ ho) {
  const int r = (blockIdx.x * 256 + threadIdx.x) * 4;
  const int c = blockIdx.y;
  const int b = blockIdx.z;
  size_t base  = ((size_t)b * T + (size_t)c * L) * N1 + r;
  size_t obase = ((size_t)b * T + (size_t)c * L) * R + r;
  float h[4];
  const f32x4 cv = *(const f32x4*)(carry + ((size_t)b * CH + c) * R + r);
  h[0] = cv[0]; h[1] = cv[1]; h[2] = cv[2]; h[3] = cv[3];
#pragma unroll 4
  for (int t = 0; t < L; ++t) {
    const bf16x4 s4 = *(const bf16x4*)(zh + base);
    const bf16x4 h4 = *(const bf16x4*)(zh + base + R);
    base += N1;
    bf16x4 o;
#pragma unroll
    for (int j = 0; j < 4; ++j) {
      const float z = 1.f / (1.f + __expf(-(float)s4[j]));
      h[j] = (1.f - z) * h[j] + z * (float)h4[j];
      o[j] = (__bf16)h[j];
    }
    *(bf16x4*)(ho + obase) = o;
    obase += R;
  }
}

extern "C" void kernel_launch(void* const* d_in, const int* in_sizes, int n_in,
                              void* d_out, int out_size, void* d_ws, size_t ws_size,
                              hipStream_t stream) {
  const float* x      = (const float*)d_in[0];
  const float* w_zh   = (const float*)d_in[1];
  const float* w_out  = (const float*)d_in[2];
  const float* conv_w = (const float*)d_in[3];
  const float* conv_b = (const float*)d_in[4];
  float* out = (float*)d_out;

  char* ws = (char*)d_ws;
  size_t off = 0;
  __bf16* wzh_b  = (__bf16*)(ws + off); off += (size_t)N1 * H * 2;        // 4 MiB
  __bf16* wout_b = (__bf16*)(ws + off); off += (size_t)H * R * 2;         // 2 MiB
  __bf16* xc     = (__bf16*)(ws + off); off += (size_t)BT * H * 2;        // 64 MiB
  __bf16* zh     = (__bf16*)(ws + off); off += (size_t)BT * N1 * 2;       // 128 MiB
  float*  carry  = (float*)(ws + off);  off += (size_t)Bb * CH * R * 4;   // 2 MiB
  // aggA/aggB alias the dead wzh_b region (4 MiB, dead after GEMM1)
  float*  aggA   = (float*)wzh_b;                                     // 2 MiB
  float*  aggB   = (float*)((char*)wzh_b + (size_t)Bb * CH * R * 4);  // 2 MiB
  __bf16* ho = xc;  // alias: xc is dead after GEMM1

  cast_f32_bf16<<<(N1 * H / 4 + 255) / 256, 256, 0, stream>>>(w_zh, wzh_b, N1 * H / 4);
  cast_f32_bf16<<<(H * R / 4 + 255) / 256, 256, 0, stream>>>(w_out, wout_b, H * R / 4);
  conv_residual_cast<<<dim3(T / 8, Bb), 256, 0, stream>>>(x, conv_w, conv_b, xc);
  // GEMM1: [32768,1024] @ [2048,1024]^T -> zh ; grid 128*8 = 1024 blocks
  gemm256<__bf16><<<(BT / 256) * (N1 / 256), 512, 0, stream>>>(xc, wzh_b, zh, BT, N1, H, N1 / 256);
  scan_pass1<<<dim3(R / 4 / 256, CH, Bb), 256, 0, stream>>>(zh, aggA, aggB);
  scan_pass2<<<Bb * R / 64, 64, 0, stream>>>(aggA, aggB, carry);
  scan_pass3<<<dim3(R / 4 / 256, CH, Bb), 256, 0, stream>>>(zh, carry, ho);
  // GEMM2: [32768,1024] @ [1024,1024]^T -> out ; grid 128*4 = 512 blocks
  gemm256<float><<<(BT / 256) * (H / 256), 512, 0, stream>>>(ho, wout_b, out, BT, H, R, H / 256);
}

// Round 6
// 538.431 us; speedup vs baseline: 1.1440x; 1.0265x over previous
//
#include <hip/hip_runtime.h>

typedef __bf16 bf16x8 __attribute__((ext_vector_type(8)));
typedef __bf16 bf16x4 __attribute__((ext_vector_type(4)));
typedef float  f32x4  __attribute__((ext_vector_type(4)));

static constexpr int Bb = 4, T = 8192, H = 1024, R = 1024;
static constexpr int BT = Bb * T;   // 32768 rows
static constexpr int N1 = 2 * R;    // 2048 (z|h columns)
static constexpr int CH = 128;      // scan chunks
static constexpr int L  = T / CH;   // 64 steps/chunk

// ---- async global -> LDS (16B per lane, wave-uniform LDS base) ----
__device__ __forceinline__ void g2lds16(const void* g, void* l) {
  __builtin_amdgcn_global_load_lds(
      (const __attribute__((address_space(1))) unsigned int*)g,
      (__attribute__((address_space(3))) unsigned int*)l, 16, 0, 0);
}

// ---- simple f32 -> bf16 cast (weights) ----
__global__ __launch_bounds__(256) void cast_f32_bf16(const float* __restrict__ in,
                                                     __bf16* __restrict__ out, int n4) {
  int i = blockIdx.x * 256 + threadIdx.x;
  if (i >= n4) return;
  const f32x4 v = *(const f32x4*)(in + (size_t)i * 4);
  bf16x4 o;
  o[0] = (__bf16)v[0]; o[1] = (__bf16)v[1]; o[2] = (__bf16)v[2]; o[3] = (__bf16)v[3];
  *(bf16x4*)(out + (size_t)i * 4) = o;
}

// ---- residual causal depthwise conv + cast to bf16, t-blocked (8 t/thread) ----
__global__ __launch_bounds__(256) void conv_residual_cast(const float* __restrict__ x,
                                                          const float* __restrict__ cw,
                                                          const float* __restrict__ cb,
                                                          __bf16* __restrict__ xc) {
  const int h  = threadIdx.x * 4;          // 256 thr * 4 = H
  const int b  = blockIdx.y;
  const int t0 = blockIdx.x * 8;
  const f32x4 w0 = *(const f32x4*)(cw + 0 * H + h);
  const f32x4 w1 = *(const f32x4*)(cw + 1 * H + h);
  const f32x4 w2 = *(const f32x4*)(cw + 2 * H + h);
  const f32x4 w3 = *(const f32x4*)(cw + 3 * H + h);
  const f32x4 bias = *(const f32x4*)(cb + h);
  size_t base = ((size_t)b * T + t0) * H + h;
  f32x4 xm3, xm2, xm1;
  if (t0 >= 3) {
    xm3 = *(const f32x4*)(x + base - 3 * H);
    xm2 = *(const f32x4*)(x + base - 2 * H);
    xm1 = *(const f32x4*)(x + base - 1 * H);
  } else {  // t0 == 0
    xm3 = f32x4{0, 0, 0, 0}; xm2 = xm3; xm1 = xm3;
  }
#pragma unroll
  for (int tt = 0; tt < 8; ++tt) {
    const f32x4 x0 = *(const f32x4*)(x + base);
    const f32x4 acc = x0 + bias + w0 * xm3 + w1 * xm2 + w2 * xm1 + w3 * x0;
    bf16x4 o;
    o[0] = (__bf16)acc[0]; o[1] = (__bf16)acc[1]; o[2] = (__bf16)acc[2]; o[3] = (__bf16)acc[3];
    *(bf16x4*)(xc + base) = o;
    xm3 = xm2; xm2 = xm1; xm1 = x0;
    base += H;
  }
}

// ============================================================================
// 256x256 GEMM, faithful m201 8-phase schedule: C = A[M,K] @ B[N,K]^T.
// 512 threads = 8 waves (2M x 4N), per-wave 128x64 via 16x16x32 MFMA, BK=64,
// dbuf LDS 128 KiB, chunk-XOR swizzle on pre-swizzled global source.
//
// Per K-tile t (4 phases, zigzag reads 12/4/8/0, SAME-phase consumption):
//  ph1: rd A02->afA(8) + Bev->bfE(4); stage Bod(t+1,nxt); lgkm(8);
//       BAR; lgkm(0); SB0; MFMA(0,0); BAR
//  ph2: rd Bod->bfO(4);               stage A13(t+1,nxt);
//       BAR; lgkm(0); SB0; MFMA(0,1); BAR
//  ph3: rd A13->afB(8);               stage A02(t+2,cur) [slot dead since ph1];
//       BAR; lgkm(0); SB0; MFMA(1,1); BAR
//  ph4:                               stage Bev(t+2,cur) [dead since ph1];
//       BAR; SB0; MFMA(1,0); vmcnt(4); BAR
// Stream runs 2-4 phases ahead of consumption; ONE counted vmcnt(4) per tile
// (allows ph3/ph4's t+2 stages outstanding; guarantees all of t+1 landed,
// since A02/Bev(t+1) were issued at t-1.ph3/ph4). All WAR windows (stage vs
// last reader of old slot data) have >=2 barriers of margin.
//
// Liveness check (queue at each ph4 vmcnt(4), oldest first):
//   [A02(t+1),BEV(t+1) | BOD(t+1),A13(t+1) | A02(t+2),BEV(t+2)] = 12 loads;
//   vmcnt(4) drains the first 8 -> tile t+1 complete, t+2 pair outstanding.
// Deadlock-free: uniform control flow, monotone counters.
// ============================================================================

#define STG_A(buf, k0, ro) g2lds16(aBase + (size_t)(r + (ro)) * K + (k0), \
                                   &sA[buf][(w8 + (ro)) * 64])
#define STG_B(buf, k0, ro) g2lds16(bBase + (size_t)(rB + (ro)) * K + (k0), \
                                   &sB[buf][(w8B + (ro)) * 64])
#define STAGE_A02(buf, kt) do { const int k0_ = (kt) * 64; STG_A(buf, k0_, 0);  STG_A(buf, k0_, 128); } while (0)
#define STAGE_A13(buf, kt) do { const int k0_ = (kt) * 64; STG_A(buf, k0_, 64); STG_A(buf, k0_, 192); } while (0)
#define STAGE_BEV(buf, kt) do { const int k0_ = (kt) * 64; STG_B(buf, k0_, 0);  STG_B(buf, k0_, 128); } while (0)
#define STAGE_BOD(buf, kt) do { const int k0_ = (kt) * 64; STG_B(buf, k0_, 32); STG_B(buf, k0_, 160); } while (0)

#define RD_A(dst, MQ, SRC) do {                                                      \
    _Pragma("unroll") for (int i_ = 0; i_ < 4; ++i_) {                               \
      const int rt_ = aRowBase + (MQ) * 64 + i_ * 16;                                \
      _Pragma("unroll") for (int ks_ = 0; ks_ < 2; ++ks_)                            \
        dst[i_][ks_] = *(const bf16x8*)&(SRC)[rt_ * 64 + (((ks_ * 4 + kg) ^ (rt_ & 7)) * 8)]; \
    } } while (0)

#define RD_B(dst, NQ, SRC) do {                                                      \
    _Pragma("unroll") for (int j_ = 0; j_ < 2; ++j_) {                               \
      const int rt_ = bRowBase + (NQ) * 32 + j_ * 16;                                \
      _Pragma("unroll") for (int ks_ = 0; ks_ < 2; ++ks_)                            \
        dst[j_][ks_] = *(const bf16x8*)&(SRC)[rt_ * 64 + (((ks_ * 4 + kg) ^ (rt_ & 7)) * 8)]; \
    } } while (0)

#define MFMA_CL(AF, BF, MQ, NQ) do {                                                 \
    __builtin_amdgcn_s_setprio(1);                                                   \
    _Pragma("unroll") for (int i_ = 0; i_ < 4; ++i_)                                 \
      _Pragma("unroll") for (int j_ = 0; j_ < 2; ++j_)                               \
        _Pragma("unroll") for (int ks_ = 0; ks_ < 2; ++ks_)                          \
          acc[(MQ) * 4 + i_][(NQ) * 2 + j_] = __builtin_amdgcn_mfma_f32_16x16x32_bf16( \
              AF[i_][ks_], BF[j_][ks_], acc[(MQ) * 4 + i_][(NQ) * 2 + j_], 0, 0, 0); \
    __builtin_amdgcn_s_setprio(0);                                                   \
  } while (0)

#define SB0 __builtin_amdgcn_sched_barrier(0)
#define BARRIER asm volatile("s_barrier" ::: "memory")
#define VMCNT4 asm volatile("s_waitcnt vmcnt(4)" ::: "memory")
#define LGKM0  asm volatile("s_waitcnt lgkmcnt(0)" ::: "memory")
#define LGKM8  asm volatile("s_waitcnt lgkmcnt(8)" ::: "memory")

#define TILE_BODY(KT, CI, NI) do {                                        \
    const int kt1 = ((KT) + 1 < NT) ? (KT) + 1 : NT - 1;                  \
    const int kt2 = ((KT) + 2 < NT) ? (KT) + 2 : NT - 1;                  \
    /* ph1 */                                                             \
    RD_A(afA, 0, sA[CI]); RD_B(bfE, 0, sB[CI]);                           \
    STAGE_BOD(NI, kt1);                                                   \
    LGKM8;                                                                \
    BARRIER; LGKM0; SB0;                                                  \
    MFMA_CL(afA, bfE, 0, 0);                                              \
    BARRIER;                                                              \
    /* ph2 */                                                             \
    RD_B(bfO, 1, sB[CI]);                                                 \
    STAGE_A13(NI, kt1);                                                   \
    BARRIER; LGKM0; SB0;                                                  \
    MFMA_CL(afA, bfO, 0, 1);                                              \
    BARRIER;                                                              \
    /* ph3 */                                                             \
    RD_A(afB, 1, sA[CI]);                                                 \
    STAGE_A02(CI, kt2);                                                   \
    BARRIER; LGKM0; SB0;                                                  \
    MFMA_CL(afB, bfO, 1, 1);                                              \
    BARRIER;                                                              \
    /* ph4 */                                                             \
    STAGE_BEV(CI, kt2);                                                   \
    BARRIER; SB0;                                                         \
    MFMA_CL(afB, bfE, 1, 0);                                              \
    VMCNT4;                                                               \
    BARRIER;                                                              \
  } while (0)

template <typename OUT_T>
__global__ __launch_bounds__(512, 2) void gemm256(const __bf16* __restrict__ A,
                                                  const __bf16* __restrict__ Bm,
                                                  OUT_T* __restrict__ C,
                                                  int M, int N, int K, int nbx) {
  __shared__ __align__(16) __bf16 sA[2][256 * 64];
  __shared__ __align__(16) __bf16 sB[2][256 * 64];
  const int tid  = threadIdx.x;
  const int wave = tid >> 6;
  const int lane = tid & 63;
  const int wm = wave >> 2;  // 0..1
  const int wn = wave & 3;   // 0..3

  // T1: bijective XCD swizzle (both launches have nwg % 8 == 0)
  const int nwg = gridDim.x;
  int wg = blockIdx.x;
  wg = (wg & 7) * (nwg >> 3) + (wg >> 3);
  const int bm0 = (wg / nbx) * 256;
  const int bn0 = (wg % nbx) * 256;

  const int NT = K >> 6;  // K-tiles of 64 (16 here; even)

  // ---- staging geometry (per-thread constants) ----
  const int r   = tid >> 3;              // 0..63 row-in-round
  const int sgc = (tid & 7) ^ (r & 7);   // pre-swizzled source chunk
  const int rB  = r + (r & 32);          // B row pattern {0-31, 64-95}
  const int w8  = wave * 8;              // wave-uniform LDS row base
  const int w8B = w8 + (w8 & 32);
  const __bf16* aBase = A  + (size_t)bm0 * K + sgc * 8;
  const __bf16* bBase = Bm + (size_t)bn0 * K + sgc * 8;

  // ---- fragment-read geometry (16x16x32) ----
  const int l15 = lane & 15;
  const int kg  = lane >> 4;             // k-group 0..3 (8 elems each)
  const int aRowBase = wm * 128 + l15;
  const int bRowBase = wn * 64 + l15;

  f32x4 acc[8][4] = {};
  bf16x8 afA[4][2], afB[4][2], bfE[2][2], bfO[2][2];

  // ---- prologue: tile0 complete + A02/Bev(1) in flight ----
  STAGE_A02(0, 0);
  STAGE_BEV(0, 0);
  STAGE_BOD(0, 0);
  STAGE_A13(0, 0);
  {
    const int k1 = NT > 1 ? 1 : 0;
    STAGE_A02(1, k1);
    STAGE_BEV(1, k1);
  }
  VMCNT4;   // tile 0 fully landed; A02/Bev(1) still in flight
  BARRIER;

  for (int kt = 0; kt < NT; kt += 2) {
    TILE_BODY(kt, 0, 1);
    TILE_BODY(kt + 1, 1, 0);
  }

  // ---- epilogue: 16x16 C/D layout: col = lane&15, row = (lane>>4)*4 + reg ----
  const int orow0 = bm0 + wm * 128 + kg * 4;
  const int ocol0 = bn0 + wn * 64 + l15;
#pragma unroll
  for (int mi = 0; mi < 8; ++mi)
#pragma unroll
    for (int nj = 0; nj < 4; ++nj) {
      const size_t rbase = (size_t)(orow0 + mi * 16);
#pragma unroll
      for (int rr = 0; rr < 4; ++rr)
        C[(rbase + rr) * N + (ocol0 + nj * 16)] = (OUT_T)acc[mi][nj][rr];
    }
}

// ---- scan pass 1: per-(b, chunk, r) aggregate (A,B): h_end = A*h_start + B ----
__global__ __launch_bounds__(256) void scan_pass1(const __bf16* __restrict__ zh,
                                                  float* __restrict__ aggA,
                                                  float* __restrict__ aggB) {
  const int r = (blockIdx.x * 256 + threadIdx.x) * 4;
  const int c = blockIdx.y;
  const int b = blockIdx.z;
  size_t base = ((size_t)b * T + (size_t)c * L) * N1 + r;
  float Aacc[4] = {1.f, 1.f, 1.f, 1.f};
  float Bacc[4] = {0.f, 0.f, 0.f, 0.f};
#pragma unroll 4
  for (int t = 0; t < L; ++t) {
    const bf16x4 s4 = *(const bf16x4*)(zh + base);
    const bf16x4 h4 = *(const bf16x4*)(zh + base + R);
    base += N1;
#pragma unroll
    for (int j = 0; j < 4; ++j) {
      const float z = 1.f / (1.f + __expf(-(float)s4[j]));
      const float a = 1.f - z;
      Bacc[j] = a * Bacc[j] + z * (float)h4[j];
      Aacc[j] *= a;
    }
  }
  const size_t o = ((size_t)b * CH + c) * R + r;
  *(f32x4*)(aggA + o) = f32x4{Aacc[0], Aacc[1], Aacc[2], Aacc[3]};
  *(f32x4*)(aggB + o) = f32x4{Bacc[0], Bacc[1], Bacc[2], Bacc[3]};
}

// ---- scan pass 2: scan the CH chunk aggregates per (b,r); write carry-in ----
__global__ __launch_bounds__(64) void scan_pass2(const float* __restrict__ aggA,
                                                 const float* __restrict__ aggB,
                                                 float* __restrict__ carry) {
  const int idx = blockIdx.x * 64 + threadIdx.x;  // b*R + r
  const int b = idx >> 10;
  const int r = idx & (R - 1);
  float h = 0.f;
#pragma unroll 8
  for (int c = 0; c < CH; ++c) {
    const size_t o = ((size_t)b * CH + c) * R + r;
    carry[o] = h;
    h = aggA[o] * h + aggB[o];
  }
}

// ---- scan pass 3: apply carry, recompute gates, emit h_o (bf16) ----
__global__ __launch_bounds__(256) void scan_pass3(const __bf16* __restrict__ zh,
                                                  const float* __restrict__ carry,
                                                  __bf16* __restrict__ ho) {
  const int r = (blockIdx.x * 256 + threadIdx.x) * 4;
  const int c = blockIdx.y;
  const int b = blockIdx.z;
  size_t base  = ((size_t)b * T + (size_t)c * L) * N1 + r;
  size_t obase = ((size_t)b * T + (size_t)c * L) * R + r;
  float h[4];
  const f32x4 cv = *(const f32x4*)(carry + ((size_t)b * CH + c) * R + r);
  h[0] = cv[0]; h[1] = cv[1]; h[2] = cv[2]; h[3] = cv[3];
#pragma unroll 4
  for (int t = 0; t < L; ++t) {
    const bf16x4 s4 = *(const bf16x4*)(zh + base);
    const bf16x4 h4 = *(const bf16x4*)(zh + base + R);
    base += N1;
    bf16x4 o;
#pragma unroll
    for (int j = 0; j < 4; ++j) {
      const float z = 1.f / (1.f + __expf(-(float)s4[j]));
      h[j] = (1.f - z) * h[j] + z * (float)h4[j];
      o[j] = (__bf16)h[j];
    }
    *(bf16x4*)(ho + obase) = o;
    obase += R;
  }
}

extern "C" void kernel_launch(void* const* d_in, const int* in_sizes, int n_in,
                              void* d_out, int out_size, void* d_ws, size_t ws_size,
                              hipStream_t stream) {
  const float* x      = (const float*)d_in[0];
  const float* w_zh   = (const float*)d_in[1];
  const float* w_out  = (const float*)d_in[2];
  const float* conv_w = (const float*)d_in[3];
  const float* conv_b = (const float*)d_in[4];
  float* out = (float*)d_out;

  char* ws = (char*)d_ws;
  size_t off = 0;
  __bf16* wzh_b  = (__bf16*)(ws + off); off += (size_t)N1 * H * 2;        // 4 MiB
  __bf16* wout_b = (__bf16*)(ws + off); off += (size_t)H * R * 2;         // 2 MiB
  __bf16* xc     = (__bf16*)(ws + off); off += (size_t)BT * H * 2;        // 64 MiB
  __bf16* zh     = (__bf16*)(ws + off); off += (size_t)BT * N1 * 2;       // 128 MiB
  float*  carry  = (float*)(ws + off);  off += (size_t)Bb * CH * R * 4;   // 2 MiB
  // aggA/aggB alias the dead wzh_b region (4 MiB, dead after GEMM1)
  float*  aggA   = (float*)wzh_b;                                     // 2 MiB
  float*  aggB   = (float*)((char*)wzh_b + (size_t)Bb * CH * R * 4);  // 2 MiB
  __bf16* ho = xc;  // alias: xc is dead after GEMM1

  cast_f32_bf16<<<(N1 * H / 4 + 255) / 256, 256, 0, stream>>>(w_zh, wzh_b, N1 * H / 4);
  cast_f32_bf16<<<(H * R / 4 + 255) / 256, 256, 0, stream>>>(w_out, wout_b, H * R / 4);
  conv_residual_cast<<<dim3(T / 8, Bb), 256, 0, stream>>>(x, conv_w, conv_b, xc);
  // GEMM1: [32768,1024] @ [2048,1024]^T -> zh ; grid 128*8 = 1024 blocks
  gemm256<__bf16><<<(BT / 256) * (N1 / 256), 512, 0, stream>>>(xc, wzh_b, zh, BT, N1, H, N1 / 256);
  scan_pass1<<<dim3(R / 4 / 256, CH, Bb), 256, 0, stream>>>(zh, aggA, aggB);
  scan_pass2<<<Bb * R / 64, 64, 0, stream>>>(aggA, aggB, carry);
  scan_pass3<<<dim3(R / 4 / 256, CH, Bb), 256, 0, stream>>>(zh, carry, ho);
  // GEMM2: [32768,1024] @ [1024,1024]^T -> out ; grid 128*4 = 512 blocks
  gemm256<float><<<(BT / 256) * (H / 256), 512, 0, stream>>>(ho, wout_b, out, BT, H, R, H / 256);
}